// Round 2
// baseline (1995.095 us; speedup 1.0000x reference)
//
#include <hip/hip_runtime.h>
#include <hip/hip_bf16.h>
#include <math.h>

#define T_DIM 2048
#define K_DIM 17
#define HID   64
#define B_DIM 32

__device__ __forceinline__ float toF(float v) { return v; }
__device__ __forceinline__ float toF(__hip_bfloat16 v) { return __bfloat162float(v); }

// ---------------------------------------------------------------------------
// Fold GCN channel-mix weights into temporal conv weights:
//   eff[blk][dt][c][o] = sum_i gw_blk[c][i] * tcn_w[blk][o][i][dt]
// BN affine: inv = s/sqrt(v+eps), shift = b - m*inv.
// eff layout: blk0: [3][3][64] (576), blk1/2: [3][64][64] (12288 each).
// ---------------------------------------------------------------------------
__global__ void fold_weights_kernel(
    const float* __restrict__ gw0, const float* __restrict__ gw1,
    const float* __restrict__ gw2, const float* __restrict__ tcn,
    const float* __restrict__ bns, const float* __restrict__ bnb,
    const float* __restrict__ bnm, const float* __restrict__ bnv,
    float* __restrict__ eff, float* __restrict__ bnc)
{
    int tid = blockIdx.x * blockDim.x + threadIdx.x;
    int stride = gridDim.x * blockDim.x;
    const int total = 576 + 2 * 12288;
    for (int idx = tid; idx < total; idx += stride) {
        int blk, dt, c, o;
        const float* gw;
        if (idx < 576) {
            blk = 0; int r = idx; dt = r / 192; r -= dt * 192; c = r / 64; o = r & 63; gw = gw0;
        } else if (idx < 576 + 12288) {
            blk = 1; int r = idx - 576; dt = r / 4096; r -= dt * 4096; c = r / 64; o = r & 63; gw = gw1;
        } else {
            blk = 2; int r = idx - 576 - 12288; dt = r / 4096; r -= dt * 4096; c = r / 64; o = r & 63; gw = gw2;
        }
        const float* tw = tcn + (size_t)blk * 64 * 64 * 3;
        float s = 0.f;
        for (int m = 0; m < 64; m++)
            s += gw[c * 64 + m] * tw[(o * 64 + m) * 3 + dt];
        eff[idx] = s;
    }
    for (int i = tid; i < 192; i += stride) {
        float inv = bns[i] * rsqrtf(bnv[i] + 1e-5f);
        bnc[i] = inv;
        bnc[192 + i] = bnb[i] - bnm[i] * inv;
    }
}

// ---------------------------------------------------------------------------
// Fused ST-GCN block. x layout [b_local, T, K, CIN] (C contiguous).
// stage 1: xg[s][c][v] = sum_k x[b, t0-DIL+s, k, c] * adj[k][v]  (LDS, fp32)
// stage 2: y = relu(conv*inv + shift) (+ residual); wave = t, lane = o.
// POOL: instead of storing y, reduce over (t,v) -> part[b_glob][bx][64].
// ---------------------------------------------------------------------------
template<int CIN, int DIL, bool RES, typename TIN, bool POOL>
__global__ __launch_bounds__(256) void stgcn_block_kernel(
    const TIN* __restrict__ x, const float* __restrict__ adj,
    const float* __restrict__ eff, const float* __restrict__ bnc, int blk,
    __hip_bfloat16* __restrict__ y, float* __restrict__ part, int b0)
{
    constexpr int TG = 4;
    constexpr int SPAN = TG + 2 * DIL;
    __shared__ float adj_s[17 * 17];
    __shared__ __align__(16) float xg_s[SPAN][CIN][20];
    __shared__ float pr[4][64];

    const int tid = threadIdx.x;
    const int b = blockIdx.y;          // local (chunk) batch index
    const int t0 = blockIdx.x * TG;

    for (int i = tid; i < 289; i += 256) adj_s[i] = adj[i];
    __syncthreads();

    // stage 1: graph conv into LDS (thread = (s, c) pair)
    for (int p = tid; p < SPAN * CIN; p += 256) {
        int s = p / CIN, c = p - s * CIN;
        int tt = t0 - DIL + s;
        float xr[17];
        if (tt >= 0 && tt < T_DIM) {
            const TIN* xp = x + ((size_t)(b * T_DIM + tt) * K_DIM) * CIN + c;
            #pragma unroll
            for (int k = 0; k < 17; k++) xr[k] = toF(xp[k * CIN]);
        } else {
            #pragma unroll
            for (int k = 0; k < 17; k++) xr[k] = 0.f;
        }
        #pragma unroll
        for (int v = 0; v < 17; v++) {
            float sum = 0.f;
            #pragma unroll
            for (int k = 0; k < 17; k++) sum += xr[k] * adj_s[k * 17 + v];
            xg_s[s][c][v] = sum;
        }
        xg_s[s][c][17] = 0.f; xg_s[s][c][18] = 0.f; xg_s[s][c][19] = 0.f;
    }
    __syncthreads();

    // stage 2: temporal conv with folded weights
    const int o = tid & 63;
    const int tl = tid >> 6;
    const int t = t0 + tl;
    float acc[17];
    #pragma unroll
    for (int v = 0; v < 17; v++) acc[v] = 0.f;

    #pragma unroll
    for (int dt = 0; dt < 3; dt++) {
        const int s = tl + dt * DIL;
        const float* ep = eff + (dt * CIN) * 64 + o;
        #pragma unroll 8
        for (int c = 0; c < CIN; c++) {
            float w = ep[c * 64];
            const float4* xg4 = (const float4*)(&xg_s[s][c][0]);
            #pragma unroll
            for (int q = 0; q < 4; q++) {
                float4 a = xg4[q];
                acc[q * 4 + 0] += w * a.x;
                acc[q * 4 + 1] += w * a.y;
                acc[q * 4 + 2] += w * a.z;
                acc[q * 4 + 3] += w * a.w;
            }
            acc[16] += w * xg_s[s][c][16];
        }
    }

    const float inv = bnc[blk * 64 + o];
    const float sh  = bnc[192 + blk * 64 + o];
    const size_t base = ((size_t)(b * T_DIM + t) * K_DIM) * HID + o;

    if (!POOL) {
        #pragma unroll
        for (int v = 0; v < 17; v++) {
            float val = fmaxf(acc[v] * inv + sh, 0.f);
            if (RES) val += toF(x[base + (size_t)v * HID]);
            y[base + (size_t)v * HID] = __float2bfloat16(val);
        }
    } else {
        float s = 0.f;
        #pragma unroll
        for (int v = 0; v < 17; v++) {
            float val = fmaxf(acc[v] * inv + sh, 0.f);
            if (RES) val += toF(x[base + (size_t)v * HID]);
            s += val;
        }
        pr[tl][o] = s;
        __syncthreads();
        if (tid < 64) {
            part[((size_t)(b0 + b) * 512 + blockIdx.x) * 64 + tid] =
                pr[0][tid] + pr[1][tid] + pr[2][tid] + pr[3][tid];
        }
    }
}

// ---------------------------------------------------------------------------
// Sum 512 partials per (b,c), mean over T*K, LayerNorm, FC. 1 wave per b.
// ---------------------------------------------------------------------------
__global__ __launch_bounds__(64) void finish_kernel(
    const float* __restrict__ part, const float* __restrict__ ln_s,
    const float* __restrict__ ln_b, const float* __restrict__ fc_w,
    const float* __restrict__ fc_b, float* __restrict__ out)
{
    const int b = blockIdx.x;
    const int c = threadIdx.x;   // 0..63
    float s = 0.f;
    for (int i = 0; i < 512; i++)
        s += part[((size_t)b * 512 + i) * 64 + c];
    float feat = s / 34816.f;    // mean over T*K

    float m = feat;
    #pragma unroll
    for (int off = 32; off > 0; off >>= 1) m += __shfl_down(m, off);
    m = __shfl(m, 0) / 64.f;
    float d = feat - m;
    float v = d * d;
    #pragma unroll
    for (int off = 32; off > 0; off >>= 1) v += __shfl_down(v, off);
    v = __shfl(v, 0) / 64.f;
    float norm = d * rsqrtf(v + 1e-5f) * ln_s[c] + ln_b[c];

    __shared__ float ns[64];
    ns[c] = norm;
    __syncthreads();
    if (c < 10) {
        float o = fc_b[c];
        for (int i = 0; i < 64; i++) o += ns[i] * fc_w[i * 10 + c];
        out[b * 10 + c] = o;
    }
}

// ---------------------------------------------------------------------------
extern "C" void kernel_launch(void* const* d_in, const int* in_sizes, int n_in,
                              void* d_out, int out_size, void* d_ws, size_t ws_size,
                              hipStream_t stream)
{
    const float* kpts = (const float*)d_in[0];
    const float* adj  = (const float*)d_in[1];
    const float* gw0  = (const float*)d_in[2];
    const float* gw1  = (const float*)d_in[3];
    const float* gw2  = (const float*)d_in[4];
    const float* tcn  = (const float*)d_in[5];
    const float* bns  = (const float*)d_in[6];
    const float* bnb  = (const float*)d_in[7];
    const float* bnm  = (const float*)d_in[8];
    const float* bnv  = (const float*)d_in[9];
    const float* lns  = (const float*)d_in[10];
    const float* lnb  = (const float*)d_in[11];
    const float* fcw  = (const float*)d_in[12];
    const float* fcb  = (const float*)d_in[13];
    float* out = (float*)d_out;

    float* ws = (float*)d_ws;
    float* eff  = ws;                               // 25152 floats
    float* bnc  = eff + 25152;                      // 384 floats
    float* part = bnc + 384;                        // B*512*64 = 1,048,576 floats
    __hip_bfloat16* bufA = (__hip_bfloat16*)(part + (size_t)B_DIM * 512 * 64);

    // choose batch chunking so two bf16 ping-pong buffers fit in ws_size
    const size_t fixed_bytes = (25152 + 384 + (size_t)B_DIM * 512 * 64) * sizeof(float);
    int chunks = 1, cb = B_DIM;
    while (chunks < 32) {
        size_t need = fixed_bytes +
            2 * (size_t)cb * T_DIM * K_DIM * HID * sizeof(__hip_bfloat16);
        if (need <= ws_size) break;
        chunks *= 2; cb = B_DIM / chunks;
    }
    __hip_bfloat16* bufB = bufA + (size_t)cb * T_DIM * K_DIM * HID;

    fold_weights_kernel<<<32, 256, 0, stream>>>(gw0, gw1, gw2, tcn,
                                                bns, bnb, bnm, bnv, eff, bnc);

    for (int ci = 0; ci < chunks; ci++) {
        int b0 = ci * cb;
        dim3 g(T_DIM / 4, cb);
        stgcn_block_kernel<3, 1, false, float, false><<<g, 256, 0, stream>>>(
            kpts + (size_t)b0 * T_DIM * K_DIM * 3, adj, eff, bnc, 0, bufA, nullptr, 0);
        stgcn_block_kernel<64, 1, true, __hip_bfloat16, false><<<g, 256, 0, stream>>>(
            bufA, adj, eff + 576, bnc, 1, bufB, nullptr, 0);
        stgcn_block_kernel<64, 2, true, __hip_bfloat16, true><<<g, 256, 0, stream>>>(
            bufB, adj, eff + 576 + 12288, bnc, 2, nullptr, part, b0);
    }

    finish_kernel<<<B_DIM, 64, 0, stream>>>(part, lns, lnb, fcw, fcb, out);
}

// Round 3
// 398.977 us; speedup vs baseline: 5.0005x; 5.0005x over previous
//
#include <hip/hip_runtime.h>
#include <hip/hip_bf16.h>
#include <math.h>

#define T_DIM 2048
#define K_DIM 17
#define HID   64
#define B_DIM 32
#define ROWS_PER_B (T_DIM * K_DIM)   // 34816

typedef short s16x8 __attribute__((ext_vector_type(8)));
typedef float f32x4 __attribute__((ext_vector_type(4)));

__device__ __forceinline__ float bf2f(short u) {
    unsigned v = ((unsigned)(unsigned short)u) << 16;
    return __builtin_bit_cast(float, v);
}
__device__ __forceinline__ short f2bf(float f) {
    __hip_bfloat16 h = __float2bfloat16(f);
    return __builtin_bit_cast(short, h);
}

// COCO skeleton sparsity: for output keypoint v, the contributing k's
// (column-v nonzeros of adj). 47 nnz vs 289 dense -> 6x less stage-1 VALU.
static constexpr int NBR_PTR[18] = {0,3,6,9,11,13,17,21,24,27,29,31,34,37,40,43,45,47};
static constexpr int NBR_K[47] = {
    0,1,2,  0,1,3,  0,2,4,  1,3,  2,4,
    5,6,7,11,  5,6,8,12,  5,7,9,  6,8,10,  7,9,  8,10,
    5,11,13,  6,12,14,  11,13,15,  12,14,16,  13,15,  14,16 };

// ---------------------------------------------------------------------------
// Fold GCN channel-mix into temporal conv weights.
//   eff0[o][dt*4+c]  (fp32, c<3, pad 0)            for block 1
//   effT[blk][o][dt*64+c] (bf16, k-contiguous)     for blocks 2,3 (B-operand)
//   bnc: inv = s/sqrt(v+eps), shift = b - m*inv
// ---------------------------------------------------------------------------
__global__ void fold_weights_kernel(
    const float* __restrict__ gw0, const float* __restrict__ gw1,
    const float* __restrict__ gw2, const float* __restrict__ tcn,
    const float* __restrict__ bns, const float* __restrict__ bnb,
    const float* __restrict__ bnm, const float* __restrict__ bnv,
    float* __restrict__ eff0, short* __restrict__ effT, float* __restrict__ bnc)
{
    int tid = blockIdx.x * blockDim.x + threadIdx.x;
    int stride = gridDim.x * blockDim.x;
    for (int idx = tid; idx < 768; idx += stride) {
        int o = idx / 12, j = idx % 12, dt = j >> 2, c = j & 3;
        float s = 0.f;
        if (c < 3)
            for (int m = 0; m < 64; m++)
                s += gw0[c * 64 + m] * tcn[(o * 64 + m) * 3 + dt];
        eff0[idx] = s;
    }
    for (int idx = tid; idx < 24576; idx += stride) {
        int blk = idx / 12288;
        int r = idx - blk * 12288;
        int o = r / 192, k = r - o * 192, dt = k >> 6, c = k & 63;
        const float* gw = blk ? gw2 : gw1;
        const float* tw = tcn + (size_t)(blk + 1) * 64 * 64 * 3;
        float s = 0.f;
        for (int m = 0; m < 64; m++)
            s += gw[c * 64 + m] * tw[(o * 64 + m) * 3 + dt];
        effT[idx] = f2bf(s);
    }
    for (int i = tid; i < 192; i += stride) {
        float inv = bns[i] * rsqrtf(bnv[i] + 1e-5f);
        bnc[i] = inv;
        bnc[192 + i] = bnb[i] - bnm[i] * inv;
    }
}

// ---------------------------------------------------------------------------
// Block 1 (CIN=3): scalar path. WG = (b, 4 t's). wave = t, lane = o.
// Weights preloaded to 12 VGPRs; xg broadcast float4 reads from LDS.
// ---------------------------------------------------------------------------
__global__ __launch_bounds__(256) void stgcn_block1_kernel(
    const float* __restrict__ x, const float* __restrict__ adj,
    const float* __restrict__ eff0, const float* __restrict__ bnc,
    short* __restrict__ y)
{
    __shared__ float adj_s[289];
    __shared__ __align__(16) float xg_s[6][3][20];

    const int tid = threadIdx.x;
    const int b = blockIdx.y;
    const int t0 = blockIdx.x * 4;

    for (int i = tid; i < 289; i += 256) adj_s[i] = adj[i];
    __syncthreads();

    if (tid < 18) {
        int s = tid / 3, c = tid - s * 3;
        int tt = t0 - 1 + s;
        float xr[17];
        if (tt >= 0 && tt < T_DIM) {
            const float* xp = x + ((size_t)(b * T_DIM + tt) * K_DIM) * 3 + c;
            #pragma unroll
            for (int k = 0; k < 17; k++) xr[k] = xp[k * 3];
        } else {
            #pragma unroll
            for (int k = 0; k < 17; k++) xr[k] = 0.f;
        }
        #pragma unroll
        for (int v = 0; v < 17; v++) {
            float s0 = 0.f;
            #pragma unroll
            for (int j = NBR_PTR[v]; j < NBR_PTR[v + 1]; j++) {
                int k = NBR_K[j];
                s0 += adj_s[k * 17 + v] * xr[k];
            }
            xg_s[s][c][v] = s0;
        }
    }
    __syncthreads();

    const int o = tid & 63;
    const int tl = tid >> 6;
    const int t = t0 + tl;

    const float4* e4 = (const float4*)(eff0 + o * 12);
    float4 w4[3] = {e4[0], e4[1], e4[2]};
    const float* wf = (const float*)w4;   // wf[dt*4+c]

    float acc[17];
    #pragma unroll
    for (int v = 0; v < 17; v++) acc[v] = 0.f;

    #pragma unroll
    for (int dt = 0; dt < 3; dt++) {
        const int s = tl + dt;
        #pragma unroll
        for (int c = 0; c < 3; c++) {
            float w = wf[dt * 4 + c];
            const float4* xg4 = (const float4*)(&xg_s[s][c][0]);
            #pragma unroll
            for (int q = 0; q < 4; q++) {
                float4 a = xg4[q];
                acc[q * 4 + 0] += w * a.x;
                acc[q * 4 + 1] += w * a.y;
                acc[q * 4 + 2] += w * a.z;
                acc[q * 4 + 3] += w * a.w;
            }
            acc[16] += w * xg_s[s][c][16];
        }
    }

    const float inv = bnc[o];
    const float sh  = bnc[192 + o];
    const size_t base = ((size_t)(b * T_DIM + t) * K_DIM) * HID + o;
    #pragma unroll
    for (int v = 0; v < 17; v++)
        y[base + (size_t)v * HID] = f2bf(fmaxf(acc[v] * inv + sh, 0.f));
}

// ---------------------------------------------------------------------------
// Blocks 2/3 (CIN=64): MFMA GEMM.  M = 256 rows of (t,v) per WG, N = 64,
// K = 192 = (dt,c).  A staged in LDS as bf16 xg[s][v][c] (row pad 72),
// B preloaded to 96 VGPRs from effT[o][k].  Epilogue: BN+ReLU+residual,
// and for POOL (block 3) an in-kernel (t,v)-reduction to part[b][wg][64].
// ---------------------------------------------------------------------------
template<int DIL, bool POOL>
__global__ __launch_bounds__(256) void stgcn_mfma_kernel(
    const short* __restrict__ x, const float* __restrict__ adj,
    const short* __restrict__ effT, const float* __restrict__ bnc, int blk,
    short* __restrict__ y, float* __restrict__ part, int b0)
{
    constexpr int SPAN = 16 + 2 * DIL;
    __shared__ float adj_s[289];
    __shared__ __align__(16) short xg[SPAN * 17 * 72];
    __shared__ float pr[4][64];

    const int tid = threadIdx.x;
    const int b = blockIdx.y;
    const int r0 = blockIdx.x * 256;
    const int t_first = r0 / 17;          // xg slice s <-> t' = t_first - DIL + s

    const int lane = tid & 63;
    const int wave = tid >> 6;
    const int col = lane & 15;
    const int kgrp = lane >> 4;

    // ---- B-fragment preload (independent of LDS staging) ----
    s16x8 bfrag[6][4];
    #pragma unroll
    for (int kk = 0; kk < 6; kk++)
        #pragma unroll
        for (int nt = 0; nt < 4; nt++) {
            int o = nt * 16 + col;
            int k0 = kk * 32 + kgrp * 8;
            bfrag[kk][nt] = *(const s16x8*)(effT + o * 192 + k0);
        }

    for (int i = tid; i < 289; i += 256) adj_s[i] = adj[i];
    __syncthreads();

    // ---- stage 1: sparse graph conv -> bf16 LDS, layout [s][v][c] ----
    for (int item = tid; item < SPAN * 32; item += 256) {
        int s = item >> 5, cp = item & 31;      // cp = c-pair
        int tt = t_first - DIL + s;
        float xr0[17], xr1[17];
        if (tt >= 0 && tt < T_DIM) {
            const short2* xp = (const short2*)(x +
                ((size_t)(b * T_DIM + tt) * K_DIM) * 64 + cp * 2);
            #pragma unroll
            for (int k = 0; k < 17; k++) {
                short2 u = xp[k * 32];
                xr0[k] = bf2f(u.x);
                xr1[k] = bf2f(u.y);
            }
        } else {
            #pragma unroll
            for (int k = 0; k < 17; k++) { xr0[k] = 0.f; xr1[k] = 0.f; }
        }
        #pragma unroll
        for (int v = 0; v < 17; v++) {
            float a0 = 0.f, a1 = 0.f;
            #pragma unroll
            for (int j = NBR_PTR[v]; j < NBR_PTR[v + 1]; j++) {
                int k = NBR_K[j];
                float w = adj_s[k * 17 + v];
                a0 += w * xr0[k];
                a1 += w * xr1[k];
            }
            short2 st; st.x = f2bf(a0); st.y = f2bf(a1);
            *(short2*)&xg[(s * 17 + v) * 72 + cp * 2] = st;
        }
    }
    __syncthreads();

    // ---- stage 2: 4 M-tiles per wave ----
    float invv[4], shv[4];
    #pragma unroll
    for (int nt = 0; nt < 4; nt++) {
        int o = nt * 16 + col;
        invv[nt] = bnc[blk * 64 + o];
        shv[nt]  = bnc[192 + blk * 64 + o];
    }

    const size_t bbase = (size_t)b * ROWS_PER_B * 64;
    float psum[4] = {0.f, 0.f, 0.f, 0.f};

    for (int tile = 0; tile < 4; tile++) {
        const int rl_a = wave * 64 + tile * 16 + col;   // A-operand row (m)
        const int rg = r0 + rl_a;
        const int t = (unsigned)rg / 17u;
        const int v = rg - t * 17;
        const int tloc = t - t_first;

        f32x4 acc[4];
        #pragma unroll
        for (int nt = 0; nt < 4; nt++) acc[nt] = (f32x4){0.f, 0.f, 0.f, 0.f};

        #pragma unroll
        for (int kk = 0; kk < 6; kk++) {
            const int s = tloc + (kk >> 1) * DIL;
            const int c0 = (kk & 1) * 32 + kgrp * 8;
            s16x8 a = *(const s16x8*)&xg[(s * 17 + v) * 72 + c0];
            #pragma unroll
            for (int nt = 0; nt < 4; nt++)
                acc[nt] = __builtin_amdgcn_mfma_f32_16x16x32_bf16(
                    a, bfrag[kk][nt], acc[nt], 0, 0, 0);
        }

        // epilogue: C/D layout col=lane&15, row=kgrp*4+reg
        const int rl0 = r0 + wave * 64 + tile * 16 + kgrp * 4;
        #pragma unroll
        for (int nt = 0; nt < 4; nt++) {
            const int o = nt * 16 + col;
            #pragma unroll
            for (int reg = 0; reg < 4; reg++) {
                size_t idx = bbase + (size_t)(rl0 + reg) * 64 + o;
                float val = fmaxf(acc[nt][reg] * invv[nt] + shv[nt], 0.f)
                          + bf2f(x[idx]);            // residual (blocks 2,3)
                if (POOL) psum[nt] += val;
                else      y[idx] = f2bf(val);
            }
        }
    }

    if (POOL) {
        #pragma unroll
        for (int nt = 0; nt < 4; nt++) {
            float vv = psum[nt];
            vv += __shfl_xor(vv, 16);
            vv += __shfl_xor(vv, 32);
            if (lane < 16) pr[wave][nt * 16 + lane] = vv;
        }
        __syncthreads();
        if (tid < 64)
            part[((size_t)(b0 + b) * 136 + blockIdx.x) * 64 + tid] =
                pr[0][tid] + pr[1][tid] + pr[2][tid] + pr[3][tid];
    }
}

// ---------------------------------------------------------------------------
// Sum 136 partials per (b,c), mean, LayerNorm, FC. 1 wave per b.
// ---------------------------------------------------------------------------
__global__ __launch_bounds__(64) void finish_kernel(
    const float* __restrict__ part, const float* __restrict__ ln_s,
    const float* __restrict__ ln_b, const float* __restrict__ fc_w,
    const float* __restrict__ fc_b, float* __restrict__ out)
{
    const int b = blockIdx.x;
    const int c = threadIdx.x;
    float s = 0.f;
    for (int i = 0; i < 136; i++)
        s += part[((size_t)b * 136 + i) * 64 + c];
    float feat = s / (float)ROWS_PER_B;

    float m = feat;
    #pragma unroll
    for (int off = 32; off > 0; off >>= 1) m += __shfl_down(m, off);
    m = __shfl(m, 0) / 64.f;
    float d = feat - m;
    float v = d * d;
    #pragma unroll
    for (int off = 32; off > 0; off >>= 1) v += __shfl_down(v, off);
    v = __shfl(v, 0) / 64.f;
    float norm = d * rsqrtf(v + 1e-5f) * ln_s[c] + ln_b[c];

    __shared__ float ns[64];
    ns[c] = norm;
    __syncthreads();
    if (c < 10) {
        float o = fc_b[c];
        for (int i = 0; i < 64; i++) o += ns[i] * fc_w[i * 10 + c];
        out[b * 10 + c] = o;
    }
}

// ---------------------------------------------------------------------------
extern "C" void kernel_launch(void* const* d_in, const int* in_sizes, int n_in,
                              void* d_out, int out_size, void* d_ws, size_t ws_size,
                              hipStream_t stream)
{
    const float* kpts = (const float*)d_in[0];
    const float* adj  = (const float*)d_in[1];
    const float* gw0  = (const float*)d_in[2];
    const float* gw1  = (const float*)d_in[3];
    const float* gw2  = (const float*)d_in[4];
    const float* tcn  = (const float*)d_in[5];
    const float* bns  = (const float*)d_in[6];
    const float* bnb  = (const float*)d_in[7];
    const float* bnm  = (const float*)d_in[8];
    const float* bnv  = (const float*)d_in[9];
    const float* lns  = (const float*)d_in[10];
    const float* lnb  = (const float*)d_in[11];
    const float* fcw  = (const float*)d_in[12];
    const float* fcb  = (const float*)d_in[13];
    float* out = (float*)d_out;

    float* ws = (float*)d_ws;
    float* eff0 = ws;                                   // 768 f
    float* bnc  = ws + 768;                             // 384 f
    float* part = ws + 1152;                            // 32*136*64 = 278528 f
    short* effT = (short*)(ws + 1152 + 278528);         // 24576 bf16
    const size_t fixed_bytes = (size_t)(1152 + 278528) * 4 + 24576 * 2; // 1,167,872

    // batch chunking so two bf16 ping-pong buffers fit in ws_size
    int chunks = 1, cb = B_DIM;
    const size_t act_per_b = (size_t)T_DIM * K_DIM * HID * 2;  // 4,456,448 B
    while (chunks < 32) {
        if (fixed_bytes + 2 * (size_t)cb * act_per_b <= ws_size) break;
        chunks *= 2; cb = B_DIM / chunks;
    }
    short* bufA = (short*)((char*)d_ws + fixed_bytes);
    short* bufB = bufA + (size_t)cb * T_DIM * K_DIM * HID;

    fold_weights_kernel<<<64, 256, 0, stream>>>(gw0, gw1, gw2, tcn,
                                                bns, bnb, bnm, bnv,
                                                eff0, effT, bnc);

    for (int ci = 0; ci < chunks; ci++) {
        int b0 = ci * cb;
        stgcn_block1_kernel<<<dim3(T_DIM / 4, cb), 256, 0, stream>>>(
            kpts + (size_t)b0 * T_DIM * K_DIM * 3, adj, eff0, bnc, bufA);
        stgcn_mfma_kernel<1, false><<<dim3(136, cb), 256, 0, stream>>>(
            bufA, adj, effT, bnc, 1, bufB, nullptr, 0);
        stgcn_mfma_kernel<2, true><<<dim3(136, cb), 256, 0, stream>>>(
            bufB, adj, effT + 12288, bnc, 2, nullptr, part, b0);
    }

    finish_kernel<<<B_DIM, 64, 0, stream>>>(part, lns, lnb, fcw, fcb, out);
}